// Round 14
// baseline (84.861 us; speedup 1.0000x reference)
//
#include <hip/hip_runtime.h>
#include <hip/hip_bf16.h>

#define B_ 8
#define S_ 2048
#define D_ 1024
#define H_ 64

typedef __attribute__((ext_vector_type(8))) short bf16x8;
typedef __attribute__((ext_vector_type(4))) float f32x4;
typedef __attribute__((ext_vector_type(4))) unsigned short u16x4;
typedef unsigned short u16;
typedef unsigned int u32;

// fold 1/sqrt(64) and log2(e) into Q so softmax can use exp2
#define QSCALE 0.18033688011112042f

static __device__ __forceinline__ u16 f2bf(float f) {
  union { float f; unsigned u; } v; v.f = f;
  unsigned r = v.u + 0x7FFFu + ((v.u >> 16) & 1u);
  return (u16)(r >> 16);
}

// Build Wt [192][1024] bf16: rows 0..63 = Wq cols, 64..127 = Wk, 128..191 = Wv.
__global__ __launch_bounds__(256) void wprep_kernel(const float* __restrict__ Wk,
                                                    const float* __restrict__ Wq,
                                                    const float* __restrict__ Wv,
                                                    u16* __restrict__ Wt) {
  const int c = blockIdx.x;  // 0..191
  const float* W = (c < 64) ? Wq : ((c < 128) ? Wk : Wv);
  const int cc = c & 63;
  for (int d = threadIdx.x; d < D_; d += blockDim.x)
    Wt[c * D_ + d] = f2bf(W[d * H_ + cc]);
}

// QKV v12: W register-hoisted ONCE (48 bf16x8/wave); x streamed LINEARLY via
// global_load_lds (row-XOR source swizzle preserves 128-B coalescing).
// Block = 512 threads = 8 waves = 4 col-groups (48 cols) x 2 k-slices (512 k).
// x: 16-row chunks (64 KB) double-buffered; raw s_barrier + counted waits so
// the next stage flies under compute+reduce. Grid = 256 blocks x 4 chunks.
__global__ __launch_bounds__(512, 2) void qkv_kernel(const float* __restrict__ x,
                                                     const u16* __restrict__ Wt,
                                                     u16* __restrict__ Qb,
                                                     u16* __restrict__ Kb,
                                                     u16* __restrict__ Vt) {
  __shared__ char xs[2][65536];      // 128 KB
  __shared__ float red[4][64][12];   // 12.25 KB

  const int tid = threadIdx.x;
  const int lane = tid & 63;
  const int w = tid >> 6;
  const int r = lane & 15;
  const int g = lane >> 4;
  const int cg = w & 3;    // col-group: cols 48*cg .. +47
  const int ks = w >> 2;   // k-slice: k in [ks*512, ks*512+512)

  // Linear stage: LDS slot L <- global (row = L>>12, off = (L&4095) ^ ((row&7)<<4)).
  // XOR only permutes 16-B slots within 128-B groups -> coalescing preserved.
#define STAGE_X(chunk, buf)                                                    \
  {                                                                            \
    const char* gb = (const char*)x + (size_t)(chunk) * 65536;                 \
    _Pragma("unroll") for (int j = 0; j < 8; ++j) {                            \
      const int L = j * 8192 + tid * 16;                                       \
      const int row = L >> 12;                                                 \
      const int off = (L & 4095) ^ ((row & 7) << 4);                           \
      __builtin_amdgcn_global_load_lds(                                        \
          (const __attribute__((address_space(1))) u32*)(gb + (size_t)row * 4096 + off), \
          (__attribute__((address_space(3))) u32*)(&xs[buf][0] + L),           \
          16, 0, 0);                                                           \
    }                                                                          \
  }

  STAGE_X(blockIdx.x, 0);  // first stage flies under the W hoist

  // ---- W fragments, loaded ONCE, register-resident (48 x bf16x8) ----
  const u16* wbase = Wt + (size_t)(cg * 48 + r) * D_ + ks * 512 + g * 8;
  bf16x8 wf[3][16];
#pragma unroll
  for (int nf = 0; nf < 3; ++nf)
#pragma unroll
    for (int s = 0; s < 16; ++s)
      wf[nf][s] = *(const bf16x8*)(wbase + (size_t)nf * 16 * D_ + s * 32);

  int cur = 0;
  const int rsw = (r & 7) << 4;

  for (int i = 0; i < 4; ++i) {
    const long row0 = ((long)blockIdx.x + (long)i * 256) * 16;

    asm volatile("s_waitcnt vmcnt(0)" ::: "memory");   // stage(i) landed
    __builtin_amdgcn_sched_barrier(0);
    __builtin_amdgcn_s_barrier();                      // all waves' stages done
    if (i < 3) STAGE_X(blockIdx.x + (i + 1) * 256, cur ^ 1);  // flies under compute+reduce
    __builtin_amdgcn_sched_barrier(0);

    const char* xb = &xs[cur][0];
    f32x4 a0 = (f32x4){0.f, 0.f, 0.f, 0.f};
    f32x4 a1 = a0, a2 = a0;
#pragma unroll
    for (int s = 0; s < 16; ++s) {
      const int c0 = ks * 2048 + s * 128 + g * 32;     // byte offset in row
      const float4 lo = *(const float4*)(xb + r * 4096 + (c0 ^ rsw));
      const float4 hi = *(const float4*)(xb + r * 4096 + ((c0 + 16) ^ rsw));
      bf16x8 a;
      a[0] = (short)f2bf(lo.x); a[1] = (short)f2bf(lo.y);
      a[2] = (short)f2bf(lo.z); a[3] = (short)f2bf(lo.w);
      a[4] = (short)f2bf(hi.x); a[5] = (short)f2bf(hi.y);
      a[6] = (short)f2bf(hi.z); a[7] = (short)f2bf(hi.w);
      a0 = __builtin_amdgcn_mfma_f32_16x16x32_bf16(a, wf[0][s], a0, 0, 0, 0);
      a1 = __builtin_amdgcn_mfma_f32_16x16x32_bf16(a, wf[1][s], a1, 0, 0, 0);
      a2 = __builtin_amdgcn_mfma_f32_16x16x32_bf16(a, wf[2][s], a2, 0, 0, 0);
    }

    // ---- k-slice reduce with RAW barrier (stage vmcnt stays in flight) ----
    if (ks == 1) {
      float* dst = &red[cg][lane][0];
      *(f32x4*)&dst[0] = a0; *(f32x4*)&dst[4] = a1; *(f32x4*)&dst[8] = a2;
    }
    asm volatile("s_waitcnt lgkmcnt(0)" ::: "memory");
    __builtin_amdgcn_sched_barrier(0);
    __builtin_amdgcn_s_barrier();
    if (ks == 0) {
      const float* src = &red[cg][lane][0];
      a0 += *(const f32x4*)&src[0];
      a1 += *(const f32x4*)&src[4];
      a2 += *(const f32x4*)&src[8];

      const int bb = (int)(row0 >> 11);
      const int srow = (int)(row0 & 2047);
      f32x4 sv[3] = {a0, a1, a2};
#pragma unroll
      for (int nf = 0; nf < 3; ++nf) {
        const int col = cg * 48 + nf * 16 + r;  // frag wholly in Q, K, or V
        if (col < 64) {
#pragma unroll
          for (int ii = 0; ii < 4; ++ii)
            Qb[(row0 + 4 * g + ii) * H_ + col] = f2bf(sv[nf][ii] * QSCALE);
        } else if (col < 128) {
#pragma unroll
          for (int ii = 0; ii < 4; ++ii)
            Kb[(row0 + 4 * g + ii) * H_ + (col - 64)] = f2bf(sv[nf][ii]);
        } else {
          u16x4 vp;
#pragma unroll
          for (int ii = 0; ii < 4; ++ii) vp[ii] = f2bf(sv[nf][ii]);
          *(u16x4*)(Vt + ((size_t)(bb * H_ + (col - 128))) * S_ + srow + 4 * g) = vp;
        }
      }
    }
    cur ^= 1;
  }
#undef STAGE_X
}

// attn7v2: attn7 (balanced {j,127-j} x 2 kv-halves, swapped QK^T, defer-max)
// + TRUE 1-tile-ahead V prefetch (vn buffer) so no per-tile load is exposed.
// Block = 4 waves; grid = 8 x 64 = 512 blocks.
__global__ __launch_bounds__(256, 2) void attn7_kernel(const u16* __restrict__ Qb,
                                                       const u16* __restrict__ Kb,
                                                       const u16* __restrict__ Vt,
                                                       float* __restrict__ out) {
  __shared__ u16 plds[4][16 * 72];
  __shared__ float plo[4][16][68];
  __shared__ float pml[4][2][16];

  const int b = blockIdx.x >> 6;
  const int j = blockIdx.x & 63;
  const int w = threadIdx.x >> 6;
  const int lane = threadIdx.x & 63;
  const int r = lane & 15;
  const int g = lane >> 4;

  const int qt = (w < 2) ? j : (127 - j);
  const int s = w & 1;
  const int q0 = qt << 4;
  const int T = (qt >> 2) + 1;          // # of 64-wide kv tiles
  const int half = (T + 1) >> 1;
  const int start = s ? half : 0;
  const int end = s ? T : half;

  // Q as B-operand: b[i] = Q[q=r][8g+i]
  const u16* Qp = Qb + ((long)(b * S_ + q0 + r)) * H_ + 8 * g;
  const bf16x8 bq0 = *(const bf16x8*)Qp;
  const bf16x8 bq1 = *(const bf16x8*)(Qp + 32);

  const u16* Kbase = Kb + (long)b * S_ * H_ + (long)r * H_ + 8 * g;
  const u16* Vbase = Vt + (long)b * H_ * S_ + (long)r * S_ + 8 * g;

  f32x4 o[4];
#pragma unroll
  for (int nf = 0; nf < 4; ++nf) o[nf] = (f32x4){0.f, 0.f, 0.f, 0.f};
  float m = -INFINITY, l = 0.f;

  u16* pw = plds[w];

  bf16x8 ka[8], vv[8], vn[8];
  if (start < end) {
    const int k0 = start << 6;
#pragma unroll
    for (int kf = 0; kf < 4; ++kf) {
      const u16* Kp = Kbase + (long)(k0 + kf * 16) * H_;
      ka[2 * kf] = *(const bf16x8*)(Kp);
      ka[2 * kf + 1] = *(const bf16x8*)(Kp + 32);
      const u16* Vp = Vbase + (long)(kf * 16) * S_ + k0;
      vv[2 * kf] = *(const bf16x8*)(Vp);
      vv[2 * kf + 1] = *(const bf16x8*)(Vp + 32);
    }
  }

  for (int kt = start; kt < end; ++kt) {
    const int k0 = kt << 6;

    // ---- S^T tile [64k x 16q] ----
    f32x4 t4[4];
#pragma unroll
    for (int kf = 0; kf < 4; ++kf) {
      f32x4 t = (f32x4){0.f, 0.f, 0.f, 0.f};
      t = __builtin_amdgcn_mfma_f32_16x16x32_bf16(ka[2 * kf], bq0, t, 0, 0, 0);
      t = __builtin_amdgcn_mfma_f32_16x16x32_bf16(ka[2 * kf + 1], bq1, t, 0, 0, 0);
      t4[kf] = t;
    }

    // ---- prefetch next K AND V tiles (full tile of latency cover) ----
    if (kt + 1 < end) {
      const int kn = (kt + 1) << 6;
#pragma unroll
      for (int kf = 0; kf < 4; ++kf) {
        const u16* Kp = Kbase + (long)(kn + kf * 16) * H_;
        ka[2 * kf] = *(const bf16x8*)(Kp);
        ka[2 * kf + 1] = *(const bf16x8*)(Kp + 32);
        const u16* Vp = Vbase + (long)(kf * 16) * S_ + kn;
        vn[2 * kf] = *(const bf16x8*)(Vp);
        vn[2 * kf + 1] = *(const bf16x8*)(Vp + 32);
      }
    }

    if (kt == T - 1) {  // diagonal tile: causal mask (k > q)
#pragma unroll
      for (int kf = 0; kf < 4; ++kf)
#pragma unroll
        for (int i = 0; i < 4; ++i) {
          const int k = k0 + kf * 16 + 4 * g + i;
          if (k > q0 + r) t4[kf][i] = -INFINITY;
        }
    }

    // ---- row max: 15 in-lane + 2 shfl ----
    float pm = t4[0][0];
#pragma unroll
    for (int kf = 0; kf < 4; ++kf)
#pragma unroll
      for (int i = 0; i < 4; ++i) pm = fmaxf(pm, t4[kf][i]);
    pm = fmaxf(pm, __shfl_xor(pm, 16));
    pm = fmaxf(pm, __shfl_xor(pm, 32));

    // ---- defer-max ----
    if (__any(pm > m + 8.f)) {
      const float mn = fmaxf(m, pm);
      const float sc = exp2f(m - mn);
      m = mn;
      l *= sc;
      float scr[4];
#pragma unroll
      for (int i = 0; i < 4; ++i) scr[i] = __shfl(sc, 4 * g + i);  // o rows = 4g+i
#pragma unroll
      for (int nf = 0; nf < 4; ++nf)
#pragma unroll
        for (int i = 0; i < 4; ++i) o[nf][i] *= scr[i];
    }

    // ---- P = exp2(S - m), in-lane sum + 2 shfl ----
    float ps = 0.f;
#pragma unroll
    for (int kf = 0; kf < 4; ++kf)
#pragma unroll
      for (int i = 0; i < 4; ++i) {
        const float p = exp2f(t4[kf][i] - m);
        t4[kf][i] = p;
        ps += p;
      }
    ps += __shfl_xor(ps, 16);
    ps += __shfl_xor(ps, 32);
    l += ps;

    // ---- P -> LDS: 4x ds_write_b64 ----
#pragma unroll
    for (int kf = 0; kf < 4; ++kf) {
      u16x4 pk;
#pragma unroll
      for (int i = 0; i < 4; ++i) pk[i] = f2bf(t4[kf][i]);
      *(u16x4*)(pw + r * 72 + kf * 16 + 4 * g) = pk;
    }

    const bf16x8 pa0 = *(const bf16x8*)(pw + r * 72 + 8 * g);
    const bf16x8 pa1 = *(const bf16x8*)(pw + r * 72 + 32 + 8 * g);

    // ---- PV (vv was prefetched a full tile ago) ----
#pragma unroll
    for (int nf = 0; nf < 4; ++nf) {
      o[nf] = __builtin_amdgcn_mfma_f32_16x16x32_bf16(pa0, vv[2 * nf], o[nf], 0, 0, 0);
      o[nf] = __builtin_amdgcn_mfma_f32_16x16x32_bf16(pa1, vv[2 * nf + 1], o[nf], 0, 0, 0);
    }

    // ---- rotate V prefetch buffer ----
    if (kt + 1 < end) {
#pragma unroll
      for (int q = 0; q < 8; ++q) vv[q] = vn[q];
    }
  }

  // ---- write partials (o rows = 4g+i; m,l live at lane r = row) ----
#pragma unroll
  for (int nf = 0; nf < 4; ++nf)
#pragma unroll
    for (int i = 0; i < 4; ++i)
      plo[w][4 * g + i][nf * 16 + r] = o[nf][i];
  if (g == 0) {
    pml[w][0][r] = m;
    pml[w][1][r] = l;
  }
  __syncthreads();

  // ---- merge the two kv-halves; each wave writes 8 rows of one q-tile ----
  const int base = (w >> 1) << 1;
  const int hlf = w & 1;
  const int qq0 = ((base == 0) ? j : (127 - j)) << 4;
#pragma unroll
  for (int rr = 0; rr < 8; ++rr) {
    const int row = hlf * 8 + rr;
    const float mA = pml[base][0][row], mB = pml[base + 1][0][row];
    const float lA = pml[base][1][row], lB = pml[base + 1][1][row];
    const float M = fmaxf(mA, mB);
    const float ea = exp2f(mA - M), eb = exp2f(mB - M);
    const float inv = 1.f / (lA * ea + lB * eb);
    const float oo = plo[base][row][lane] * ea + plo[base + 1][row][lane] * eb;
    out[((long)(b * S_ + qq0 + row)) * H_ + lane] = oo * inv;
  }
}

extern "C" void kernel_launch(void* const* d_in, const int* in_sizes, int n_in,
                              void* d_out, int out_size, void* d_ws, size_t ws_size,
                              hipStream_t stream) {
  const float* x  = (const float*)d_in[0];
  const float* Wk = (const float*)d_in[1];
  const float* Wq = (const float*)d_in[2];
  const float* Wv = (const float*)d_in[3];
  float* out = (float*)d_out;

  u16* Qb = (u16*)d_ws;                                   // 2 MiB
  u16* Kb = Qb + (long)B_ * S_ * H_;                      // 2 MiB
  u16* Vt = Kb + (long)B_ * S_ * H_;                      // 2 MiB
  u16* Wt = Vt + (long)B_ * S_ * H_;                      // 384 KiB

  wprep_kernel<<<192, 256, 0, stream>>>(Wk, Wq, Wv, Wt);
  qkv_kernel<<<256, 512, 0, stream>>>(x, Wt, Qb, Kb, Vt);
  attn7_kernel<<<B_ * 64, 256, 0, stream>>>(Qb, Kb, Vt, out);
}

// Round 15
// 62.377 us; speedup vs baseline: 1.3605x; 1.3605x over previous
//
#include <hip/hip_runtime.h>
#include <hip/hip_bf16.h>

#define B_ 8
#define S_ 2048
#define D_ 1024
#define H_ 64

typedef __attribute__((ext_vector_type(8))) short bf16x8;
typedef __attribute__((ext_vector_type(4))) float f32x4;
typedef __attribute__((ext_vector_type(4))) unsigned short u16x4;
typedef unsigned short u16;
typedef unsigned int u32;

// fold 1/sqrt(64) and log2(e) into Q so softmax can use exp2
#define QSCALE 0.18033688011112042f

static __device__ __forceinline__ u16 f2bf(float f) {
  union { float f; unsigned u; } v; v.f = f;
  unsigned r = v.u + 0x7FFFu + ((v.u >> 16) & 1u);
  return (u16)(r >> 16);
}

// Build Wt [192][1024] bf16: rows 0..63 = Wq cols, 64..127 = Wk, 128..191 = Wv.
__global__ __launch_bounds__(256) void wprep_kernel(const float* __restrict__ Wk,
                                                    const float* __restrict__ Wq,
                                                    const float* __restrict__ Wv,
                                                    u16* __restrict__ Wt) {
  const int c = blockIdx.x;  // 0..191
  const float* W = (c < 64) ? Wq : ((c < 128) ? Wk : Wv);
  const int cc = c & 63;
  for (int d = threadIdx.x; d < D_; d += blockDim.x)
    Wt[c * D_ + d] = f2bf(W[d * H_ + cc]);
}

// QKV v13: v10's proven LDS-DMA pipeline, widened to 512 threads/block.
// Block = 8 waves = 4 col-groups (48 cols) x 2 row-groups (16 rows); wave
// computes 3 frags (acc ~12 VGPR -> VGPR ~60, no hoist-collapse risk).
// LDS 64 KB -> 2 blocks/CU -> 16 waves/CU (2x v10's TLP). 16 chunks of BK=64.
__global__ __launch_bounds__(512, 4) void qkv_kernel(const float* __restrict__ x,
                                                     const u16* __restrict__ Wt,
                                                     u16* __restrict__ Qb,
                                                     u16* __restrict__ Kb,
                                                     u16* __restrict__ Vt) {
  __shared__ char sh[65536];  // xs: 2 x [32][64] f32 (16 KB); ws: 2 x [192][64] bf16 (48 KB)
  char* const xsb = sh;
  char* const wsb = sh + 16384;

  const int tid = threadIdx.x;
  const int w = tid >> 6;
  const int lane = tid & 63;
  const int r = lane & 15;
  const int g = lane >> 4;
  const int rg = w >> 2;   // row-group 0/1
  const int cg = w & 3;    // col-group 0..3

  const long row0 = (long)blockIdx.x * 32;

  // x tile [32 rows][64 k] fp32, row stride 256 B; swizzle bits 4-6 by row&7.
  // 8 KB = 1 load/thread.
#define STAGE_X(kc, buf)                                                       \
  {                                                                            \
    const char* gb = (const char*)x + (size_t)row0 * 4096 + (size_t)(kc) * 256;\
    const int L = tid * 16;                                                    \
    const int row = L >> 8;                                                    \
    const int sw = (L & 255) ^ ((row & 7) << 4);                               \
    __builtin_amdgcn_global_load_lds(                                          \
        (const __attribute__((address_space(1))) u32*)(gb + (size_t)row * 4096 + sw), \
        (__attribute__((address_space(3))) u32*)(xsb + (buf) * 8192 + L),      \
        16, 0, 0);                                                             \
  }

  // W tile [192 cols][64 k] bf16, col stride 128 B; swizzle bits 4-6 by col&7.
  // 24 KB = 3 loads/thread.
#define STAGE_W(kc, buf)                                                       \
  {                                                                            \
    const char* gb = (const char*)Wt + (size_t)(kc) * 128;                     \
    _Pragma("unroll") for (int j = 0; j < 3; ++j) {                            \
      const int L = j * 8192 + tid * 16;                                       \
      const int col = L >> 7;                                                  \
      const int sw = (L & 127) ^ ((col & 7) << 4);                             \
      __builtin_amdgcn_global_load_lds(                                        \
          (const __attribute__((address_space(1))) u32*)(gb + (size_t)col * 2048 + sw), \
          (__attribute__((address_space(3))) u32*)(wsb + (buf) * 24576 + L),   \
          16, 0, 0);                                                           \
    }                                                                          \
  }

  f32x4 acc[3];
#pragma unroll
  for (int nf = 0; nf < 3; ++nf) acc[nf] = (f32x4){0.f, 0.f, 0.f, 0.f};

  STAGE_X(0, 0);
  STAGE_W(0, 0);
  int cur = 0;

  const int rr = rg * 16 + r;
  const int xswz = (rr & 7) << 4;

  for (int kc = 0; kc < 16; ++kc) {
    __syncthreads();  // stage(kc) complete (vmcnt drained here, by design)
    if (kc < 15) {
      STAGE_X(kc + 1, cur ^ 1);
      STAGE_W(kc + 1, cur ^ 1);
    }
    __builtin_amdgcn_sched_barrier(0);  // keep stage issue above compute

    const char* xb = xsb + cur * 8192;
    const char* wb = wsb + cur * 24576;
#pragma unroll
    for (int ks = 0; ks < 2; ++ks) {
      const int cb = ks * 128 + g * 32;
      const float4 lo = *(const float4*)(xb + rr * 256 + (cb ^ xswz));
      const float4 hi = *(const float4*)(xb + rr * 256 + ((cb + 16) ^ xswz));
      bf16x8 a;
      a[0] = (short)f2bf(lo.x); a[1] = (short)f2bf(lo.y);
      a[2] = (short)f2bf(lo.z); a[3] = (short)f2bf(lo.w);
      a[4] = (short)f2bf(hi.x); a[5] = (short)f2bf(hi.y);
      a[6] = (short)f2bf(hi.z); a[7] = (short)f2bf(hi.w);
#pragma unroll
      for (int nf = 0; nf < 3; ++nf) {
        const int col = cg * 48 + nf * 16 + r;
        const int wcb = (ks * 64 + g * 16) ^ ((col & 7) << 4);
        const bf16x8 b = *(const bf16x8*)(wb + col * 128 + wcb);
        acc[nf] = __builtin_amdgcn_mfma_f32_16x16x32_bf16(a, b, acc[nf], 0, 0, 0);
      }
    }
    cur ^= 1;
  }
#undef STAGE_W
#undef STAGE_X

  // ---- epilogue: wave owns rows rg*16..+15, cols cg*48..+47 exclusively ----
  const int bb = (int)(row0 >> 11);
  const int srow = (int)(row0 & 2047) + rg * 16;
#pragma unroll
  for (int nf = 0; nf < 3; ++nf) {
    const int col = cg * 48 + nf * 16 + r;  // frag wholly in Q, K, or V
    if (col < 64) {
#pragma unroll
      for (int ii = 0; ii < 4; ++ii)
        Qb[(row0 + rg * 16 + 4 * g + ii) * H_ + col] = f2bf(acc[nf][ii] * QSCALE);
    } else if (col < 128) {
#pragma unroll
      for (int ii = 0; ii < 4; ++ii)
        Kb[(row0 + rg * 16 + 4 * g + ii) * H_ + (col - 64)] = f2bf(acc[nf][ii]);
    } else {
      u16x4 vp;
#pragma unroll
      for (int ii = 0; ii < 4; ++ii) vp[ii] = f2bf(acc[nf][ii]);
      *(u16x4*)(Vt + ((size_t)(bb * H_ + (col - 128))) * S_ + srow + 4 * g) = vp;
    }
  }
}

// attn7 (round-12 verbatim, measured ~37 us): balanced {j,127-j} x 2 kv-halves
// + swapped QK^T core (P-row in-lane: 2 shfl not 8) + defer-max.
__global__ __launch_bounds__(256, 2) void attn7_kernel(const u16* __restrict__ Qb,
                                                       const u16* __restrict__ Kb,
                                                       const u16* __restrict__ Vt,
                                                       float* __restrict__ out) {
  __shared__ u16 plds[4][16 * 72];
  __shared__ float plo[4][16][68];
  __shared__ float pml[4][2][16];

  const int b = blockIdx.x >> 6;
  const int j = blockIdx.x & 63;
  const int w = threadIdx.x >> 6;
  const int lane = threadIdx.x & 63;
  const int r = lane & 15;
  const int g = lane >> 4;

  const int qt = (w < 2) ? j : (127 - j);
  const int s = w & 1;
  const int q0 = qt << 4;
  const int T = (qt >> 2) + 1;          // # of 64-wide kv tiles
  const int half = (T + 1) >> 1;
  const int start = s ? half : 0;
  const int end = s ? T : half;

  // Q as B-operand: b[i] = Q[q=r][8g+i]
  const u16* Qp = Qb + ((long)(b * S_ + q0 + r)) * H_ + 8 * g;
  const bf16x8 bq0 = *(const bf16x8*)Qp;
  const bf16x8 bq1 = *(const bf16x8*)(Qp + 32);

  const u16* Kbase = Kb + (long)b * S_ * H_ + (long)r * H_ + 8 * g;
  const u16* Vbase = Vt + (long)b * H_ * S_ + (long)r * S_ + 8 * g;

  f32x4 o[4];
#pragma unroll
  for (int nf = 0; nf < 4; ++nf) o[nf] = (f32x4){0.f, 0.f, 0.f, 0.f};
  float m = -INFINITY, l = 0.f;

  u16* pw = plds[w];

  bf16x8 ka[8];  // K as A-operand: a[i] = K[k0+16kf+r][8g+i]
  if (start < end) {
    const int k0 = start << 6;
#pragma unroll
    for (int kf = 0; kf < 4; ++kf) {
      const u16* Kp = Kbase + (long)(k0 + kf * 16) * H_;
      ka[2 * kf] = *(const bf16x8*)(Kp);
      ka[2 * kf + 1] = *(const bf16x8*)(Kp + 32);
    }
  }

  for (int kt = start; kt < end; ++kt) {
    const int k0 = kt << 6;

    // ---- S^T tile [64k x 16q]: rows k (4g+i within 16kf), col q=r ----
    f32x4 t4[4];
#pragma unroll
    for (int kf = 0; kf < 4; ++kf) {
      f32x4 t = (f32x4){0.f, 0.f, 0.f, 0.f};
      t = __builtin_amdgcn_mfma_f32_16x16x32_bf16(ka[2 * kf], bq0, t, 0, 0, 0);
      t = __builtin_amdgcn_mfma_f32_16x16x32_bf16(ka[2 * kf + 1], bq1, t, 0, 0, 0);
      t4[kf] = t;
    }

    // ---- early V loads (fly under softmax) ----
    bf16x8 vv[8];
#pragma unroll
    for (int nf = 0; nf < 4; ++nf) {
      const u16* Vp = Vbase + (long)(nf * 16) * S_ + k0;
      vv[2 * nf] = *(const bf16x8*)(Vp);
      vv[2 * nf + 1] = *(const bf16x8*)(Vp + 32);
    }
    // ---- prefetch next K tile ----
    if (kt + 1 < end) {
      const int kn = (kt + 1) << 6;
#pragma unroll
      for (int kf = 0; kf < 4; ++kf) {
        const u16* Kp = Kbase + (long)(kn + kf * 16) * H_;
        ka[2 * kf] = *(const bf16x8*)(Kp);
        ka[2 * kf + 1] = *(const bf16x8*)(Kp + 32);
      }
    }

    if (kt == T - 1) {  // diagonal tile: causal mask (k > q)
#pragma unroll
      for (int kf = 0; kf < 4; ++kf)
#pragma unroll
        for (int i = 0; i < 4; ++i) {
          const int k = k0 + kf * 16 + 4 * g + i;
          if (k > q0 + r) t4[kf][i] = -INFINITY;
        }
    }

    // ---- row max: 15 in-lane + 2 shfl (row q=r replicated over g) ----
    float pm = t4[0][0];
#pragma unroll
    for (int kf = 0; kf < 4; ++kf)
#pragma unroll
      for (int i = 0; i < 4; ++i) pm = fmaxf(pm, t4[kf][i]);
    pm = fmaxf(pm, __shfl_xor(pm, 16));
    pm = fmaxf(pm, __shfl_xor(pm, 32));

    // ---- defer-max: rescale only when max grew past threshold ----
    if (__any(pm > m + 8.f)) {
      const float mn = fmaxf(m, pm);
      const float sc = exp2f(m - mn);
      m = mn;
      l *= sc;
      float scr[4];
#pragma unroll
      for (int i = 0; i < 4; ++i) scr[i] = __shfl(sc, 4 * g + i);  // o rows = 4g+i
#pragma unroll
      for (int nf = 0; nf < 4; ++nf)
#pragma unroll
        for (int i = 0; i < 4; ++i) o[nf][i] *= scr[i];
    }

    // ---- P = exp2(S - m), in-lane sum + 2 shfl ----
    float ps = 0.f;
#pragma unroll
    for (int kf = 0; kf < 4; ++kf)
#pragma unroll
      for (int i = 0; i < 4; ++i) {
        const float p = exp2f(t4[kf][i] - m);
        t4[kf][i] = p;
        ps += p;
      }
    ps += __shfl_xor(ps, 16);
    ps += __shfl_xor(ps, 32);
    l += ps;

    // ---- P -> LDS: 4x ds_write_b64 (row q=r, k contiguous) ----
#pragma unroll
    for (int kf = 0; kf < 4; ++kf) {
      u16x4 pk;
#pragma unroll
      for (int i = 0; i < 4; ++i) pk[i] = f2bf(t4[kf][i]);
      *(u16x4*)(pw + r * 72 + kf * 16 + 4 * g) = pk;
    }

    const bf16x8 pa0 = *(const bf16x8*)(pw + r * 72 + 8 * g);
    const bf16x8 pa1 = *(const bf16x8*)(pw + r * 72 + 32 + 8 * g);

    // ---- PV: O[16q x 64h] += P * V ----
#pragma unroll
    for (int nf = 0; nf < 4; ++nf) {
      o[nf] = __builtin_amdgcn_mfma_f32_16x16x32_bf16(pa0, vv[2 * nf], o[nf], 0, 0, 0);
      o[nf] = __builtin_amdgcn_mfma_f32_16x16x32_bf16(pa1, vv[2 * nf + 1], o[nf], 0, 0, 0);
    }
  }

  // ---- write partials (o rows = 4g+i; m,l live at lane r = row) ----
#pragma unroll
  for (int nf = 0; nf < 4; ++nf)
#pragma unroll
    for (int i = 0; i < 4; ++i)
      plo[w][4 * g + i][nf * 16 + r] = o[nf][i];
  if (g == 0) {
    pml[w][0][r] = m;
    pml[w][1][r] = l;
  }
  __syncthreads();

  // ---- merge the two kv-halves; each wave writes 8 rows of one q-tile ----
  const int base = (w >> 1) << 1;
  const int hlf = w & 1;
  const int qq0 = ((base == 0) ? j : (127 - j)) << 4;
#pragma unroll
  for (int rr = 0; rr < 8; ++rr) {
    const int row = hlf * 8 + rr;
    const float mA = pml[base][0][row], mB = pml[base + 1][0][row];
    const float lA = pml[base][1][row], lB = pml[base + 1][1][row];
    const float M = fmaxf(mA, mB);
    const float ea = exp2f(mA - M), eb = exp2f(mB - M);
    const float inv = 1.f / (lA * ea + lB * eb);
    const float oo = plo[base][row][lane] * ea + plo[base + 1][row][lane] * eb;
    out[((long)(b * S_ + qq0 + row)) * H_ + lane] = oo * inv;
  }
}

extern "C" void kernel_launch(void* const* d_in, const int* in_sizes, int n_in,
                              void* d_out, int out_size, void* d_ws, size_t ws_size,
                              hipStream_t stream) {
  const float* x  = (const float*)d_in[0];
  const float* Wk = (const float*)d_in[1];
  const float* Wq = (const float*)d_in[2];
  const float* Wv = (const float*)d_in[3];
  float* out = (float*)d_out;

  u16* Qb = (u16*)d_ws;                                   // 2 MiB
  u16* Kb = Qb + (long)B_ * S_ * H_;                      // 2 MiB
  u16* Vt = Kb + (long)B_ * S_ * H_;                      // 2 MiB
  u16* Wt = Vt + (long)B_ * S_ * H_;                      // 384 KiB

  wprep_kernel<<<192, 256, 0, stream>>>(Wk, Wq, Wv, Wt);
  qkv_kernel<<<512, 512, 0, stream>>>(x, Wt, Qb, Kb, Vt);
  attn7_kernel<<<B_ * 64, 256, 0, stream>>>(Qb, Kb, Vt, out);
}

// Round 16
// 60.944 us; speedup vs baseline: 1.3924x; 1.0235x over previous
//
#include <hip/hip_runtime.h>
#include <hip/hip_bf16.h>

#define B_ 8
#define S_ 2048
#define D_ 1024
#define H_ 64

typedef __attribute__((ext_vector_type(8))) short bf16x8;
typedef __attribute__((ext_vector_type(4))) float f32x4;
typedef __attribute__((ext_vector_type(4))) unsigned short u16x4;
typedef unsigned short u16;
typedef unsigned int u32;

// fold 1/sqrt(64) and log2(e) into Q so softmax can use exp2
#define QSCALE 0.18033688011112042f

static __device__ __forceinline__ u16 f2bf(float f) {
  union { float f; unsigned u; } v; v.f = f;
  unsigned r = v.u + 0x7FFFu + ((v.u >> 16) & 1u);
  return (u16)(r >> 16);
}

// Build Wt [192][1024] bf16: rows 0..63 = Wq cols, 64..127 = Wk, 128..191 = Wv.
__global__ __launch_bounds__(256) void wprep_kernel(const float* __restrict__ Wk,
                                                    const float* __restrict__ Wq,
                                                    const float* __restrict__ Wv,
                                                    u16* __restrict__ Wt) {
  const int c = blockIdx.x;  // 0..191
  const float* W = (c < 64) ? Wq : ((c < 128) ? Wk : Wv);
  const int cc = c & 63;
  for (int d = threadIdx.x; d < D_; d += blockDim.x)
    Wt[c * D_ + d] = f2bf(W[d * H_ + cc]);
}

// QKV v13 + batch->XCD pinning: block bid handles batch (bid&7), row-group
// (bid>>3); with round-robin XCD = blockIdx%8 this pins each batch's K/V
// WRITES to the XCD whose L2 the attention kernel will read them from.
// Structure identical to round-15 v13 (8 waves, LDS-DMA dbuf, BK=64).
__global__ __launch_bounds__(512, 4) void qkv_kernel(const float* __restrict__ x,
                                                     const u16* __restrict__ Wt,
                                                     u16* __restrict__ Qb,
                                                     u16* __restrict__ Kb,
                                                     u16* __restrict__ Vt) {
  __shared__ char sh[65536];  // xs: 2 x [32][64] f32 (16 KB); ws: 2 x [192][64] bf16 (48 KB)
  char* const xsb = sh;
  char* const wsb = sh + 16384;

  const int tid = threadIdx.x;
  const int w = tid >> 6;
  const int lane = tid & 63;
  const int r = lane & 15;
  const int g = lane >> 4;
  const int rg = w >> 2;   // row-group 0/1
  const int cg = w & 3;    // col-group 0..3

  const int bpin = blockIdx.x & 7;       // batch == XCD
  const int jj = blockIdx.x >> 3;        // 0..63 row-group within batch
  const long row0 = ((long)bpin * 64 + jj) * 32;

#define STAGE_X(kc, buf)                                                       \
  {                                                                            \
    const char* gb = (const char*)x + (size_t)row0 * 4096 + (size_t)(kc) * 256;\
    const int L = tid * 16;                                                    \
    const int row = L >> 8;                                                    \
    const int sw = (L & 255) ^ ((row & 7) << 4);                               \
    __builtin_amdgcn_global_load_lds(                                          \
        (const __attribute__((address_space(1))) u32*)(gb + (size_t)row * 4096 + sw), \
        (__attribute__((address_space(3))) u32*)(xsb + (buf) * 8192 + L),      \
        16, 0, 0);                                                             \
  }

#define STAGE_W(kc, buf)                                                       \
  {                                                                            \
    const char* gb = (const char*)Wt + (size_t)(kc) * 128;                     \
    _Pragma("unroll") for (int j2 = 0; j2 < 3; ++j2) {                         \
      const int L = j2 * 8192 + tid * 16;                                      \
      const int col = L >> 7;                                                  \
      const int sw = (L & 127) ^ ((col & 7) << 4);                             \
      __builtin_amdgcn_global_load_lds(                                        \
          (const __attribute__((address_space(1))) u32*)(gb + (size_t)col * 2048 + sw), \
          (__attribute__((address_space(3))) u32*)(wsb + (buf) * 24576 + L),   \
          16, 0, 0);                                                           \
    }                                                                          \
  }

  f32x4 acc[3];
#pragma unroll
  for (int nf = 0; nf < 3; ++nf) acc[nf] = (f32x4){0.f, 0.f, 0.f, 0.f};

  STAGE_X(0, 0);
  STAGE_W(0, 0);
  int cur = 0;

  const int rr = rg * 16 + r;
  const int xswz = (rr & 7) << 4;

  for (int kc = 0; kc < 16; ++kc) {
    __syncthreads();  // stage(kc) complete (vmcnt drained here, by design)
    if (kc < 15) {
      STAGE_X(kc + 1, cur ^ 1);
      STAGE_W(kc + 1, cur ^ 1);
    }
    __builtin_amdgcn_sched_barrier(0);  // keep stage issue above compute

    const char* xb = xsb + cur * 8192;
    const char* wb = wsb + cur * 24576;
#pragma unroll
    for (int ks = 0; ks < 2; ++ks) {
      const int cb = ks * 128 + g * 32;
      const float4 lo = *(const float4*)(xb + rr * 256 + (cb ^ xswz));
      const float4 hi = *(const float4*)(xb + rr * 256 + ((cb + 16) ^ xswz));
      bf16x8 a;
      a[0] = (short)f2bf(lo.x); a[1] = (short)f2bf(lo.y);
      a[2] = (short)f2bf(lo.z); a[3] = (short)f2bf(lo.w);
      a[4] = (short)f2bf(hi.x); a[5] = (short)f2bf(hi.y);
      a[6] = (short)f2bf(hi.z); a[7] = (short)f2bf(hi.w);
#pragma unroll
      for (int nf = 0; nf < 3; ++nf) {
        const int col = cg * 48 + nf * 16 + r;
        const int wcb = (ks * 64 + g * 16) ^ ((col & 7) << 4);
        const bf16x8 b = *(const bf16x8*)(wb + col * 128 + wcb);
        acc[nf] = __builtin_amdgcn_mfma_f32_16x16x32_bf16(a, b, acc[nf], 0, 0, 0);
      }
    }
    cur ^= 1;
  }
#undef STAGE_W
#undef STAGE_X

  // ---- epilogue: wave owns rows rg*16..+15, cols cg*48..+47 exclusively ----
  const int bb = (int)(row0 >> 11);
  const int srow = (int)(row0 & 2047) + rg * 16;
#pragma unroll
  for (int nf = 0; nf < 3; ++nf) {
    const int col = cg * 48 + nf * 16 + r;  // frag wholly in Q, K, or V
    if (col < 64) {
#pragma unroll
      for (int ii = 0; ii < 4; ++ii)
        Qb[(row0 + rg * 16 + 4 * g + ii) * H_ + col] = f2bf(acc[nf][ii] * QSCALE);
    } else if (col < 128) {
#pragma unroll
      for (int ii = 0; ii < 4; ++ii)
        Kb[(row0 + rg * 16 + 4 * g + ii) * H_ + (col - 64)] = f2bf(acc[nf][ii]);
    } else {
      u16x4 vp;
#pragma unroll
      for (int ii = 0; ii < 4; ++ii) vp[ii] = f2bf(acc[nf][ii]);
      *(u16x4*)(Vt + ((size_t)(bb * H_ + (col - 128))) * S_ + srow + 4 * g) = vp;
    }
  }
}

// attn7 + batch->XCD pinning: b = blockIdx&7 so all 64 blocks of a batch run
// on one XCD; per-XCD K/V/Q working set ~768 KB fits the 4 MB L2.
// Body identical to round-15 attn7 (balanced {j,127-j} x 2 halves, swapped
// QK^T, defer-max).
__global__ __launch_bounds__(256, 2) void attn7_kernel(const u16* __restrict__ Qb,
                                                       const u16* __restrict__ Kb,
                                                       const u16* __restrict__ Vt,
                                                       float* __restrict__ out) {
  __shared__ u16 plds[4][16 * 72];
  __shared__ float plo[4][16][68];
  __shared__ float pml[4][2][16];

  const int b = blockIdx.x & 7;        // batch == XCD
  const int j = blockIdx.x >> 3;       // 0..63
  const int w = threadIdx.x >> 6;
  const int lane = threadIdx.x & 63;
  const int r = lane & 15;
  const int g = lane >> 4;

  const int qt = (w < 2) ? j : (127 - j);
  const int s = w & 1;
  const int q0 = qt << 4;
  const int T = (qt >> 2) + 1;          // # of 64-wide kv tiles
  const int half = (T + 1) >> 1;
  const int start = s ? half : 0;
  const int end = s ? T : half;

  // Q as B-operand: b[i] = Q[q=r][8g+i]
  const u16* Qp = Qb + ((long)(b * S_ + q0 + r)) * H_ + 8 * g;
  const bf16x8 bq0 = *(const bf16x8*)Qp;
  const bf16x8 bq1 = *(const bf16x8*)(Qp + 32);

  const u16* Kbase = Kb + (long)b * S_ * H_ + (long)r * H_ + 8 * g;
  const u16* Vbase = Vt + (long)b * H_ * S_ + (long)r * S_ + 8 * g;

  f32x4 o[4];
#pragma unroll
  for (int nf = 0; nf < 4; ++nf) o[nf] = (f32x4){0.f, 0.f, 0.f, 0.f};
  float m = -INFINITY, l = 0.f;

  u16* pw = plds[w];

  bf16x8 ka[8];  // K as A-operand: a[i] = K[k0+16kf+r][8g+i]
  if (start < end) {
    const int k0 = start << 6;
#pragma unroll
    for (int kf = 0; kf < 4; ++kf) {
      const u16* Kp = Kbase + (long)(k0 + kf * 16) * H_;
      ka[2 * kf] = *(const bf16x8*)(Kp);
      ka[2 * kf + 1] = *(const bf16x8*)(Kp + 32);
    }
  }

  for (int kt = start; kt < end; ++kt) {
    const int k0 = kt << 6;

    // ---- S^T tile [64k x 16q]: rows k (4g+i within 16kf), col q=r ----
    f32x4 t4[4];
#pragma unroll
    for (int kf = 0; kf < 4; ++kf) {
      f32x4 t = (f32x4){0.f, 0.f, 0.f, 0.f};
      t = __builtin_amdgcn_mfma_f32_16x16x32_bf16(ka[2 * kf], bq0, t, 0, 0, 0);
      t = __builtin_amdgcn_mfma_f32_16x16x32_bf16(ka[2 * kf + 1], bq1, t, 0, 0, 0);
      t4[kf] = t;
    }

    // ---- early V loads (fly under softmax) ----
    bf16x8 vv[8];
#pragma unroll
    for (int nf = 0; nf < 4; ++nf) {
      const u16* Vp = Vbase + (long)(nf * 16) * S_ + k0;
      vv[2 * nf] = *(const bf16x8*)(Vp);
      vv[2 * nf + 1] = *(const bf16x8*)(Vp + 32);
    }
    // ---- prefetch next K tile ----
    if (kt + 1 < end) {
      const int kn = (kt + 1) << 6;
#pragma unroll
      for (int kf = 0; kf < 4; ++kf) {
        const u16* Kp = Kbase + (long)(kn + kf * 16) * H_;
        ka[2 * kf] = *(const bf16x8*)(Kp);
        ka[2 * kf + 1] = *(const bf16x8*)(Kp + 32);
      }
    }

    if (kt == T - 1) {  // diagonal tile: causal mask (k > q)
#pragma unroll
      for (int kf = 0; kf < 4; ++kf)
#pragma unroll
        for (int i = 0; i < 4; ++i) {
          const int k = k0 + kf * 16 + 4 * g + i;
          if (k > q0 + r) t4[kf][i] = -INFINITY;
        }
    }

    // ---- row max: 15 in-lane + 2 shfl (row q=r replicated over g) ----
    float pm = t4[0][0];
#pragma unroll
    for (int kf = 0; kf < 4; ++kf)
#pragma unroll
      for (int i = 0; i < 4; ++i) pm = fmaxf(pm, t4[kf][i]);
    pm = fmaxf(pm, __shfl_xor(pm, 16));
    pm = fmaxf(pm, __shfl_xor(pm, 32));

    // ---- defer-max: rescale only when max grew past threshold ----
    if (__any(pm > m + 8.f)) {
      const float mn = fmaxf(m, pm);
      const float sc = exp2f(m - mn);
      m = mn;
      l *= sc;
      float scr[4];
#pragma unroll
      for (int i = 0; i < 4; ++i) scr[i] = __shfl(sc, 4 * g + i);  // o rows = 4g+i
#pragma unroll
      for (int nf = 0; nf < 4; ++nf)
#pragma unroll
        for (int i = 0; i < 4; ++i) o[nf][i] *= scr[i];
    }

    // ---- P = exp2(S - m), in-lane sum + 2 shfl ----
    float ps = 0.f;
#pragma unroll
    for (int kf = 0; kf < 4; ++kf)
#pragma unroll
      for (int i = 0; i < 4; ++i) {
        const float p = exp2f(t4[kf][i] - m);
        t4[kf][i] = p;
        ps += p;
      }
    ps += __shfl_xor(ps, 16);
    ps += __shfl_xor(ps, 32);
    l += ps;

    // ---- P -> LDS: 4x ds_write_b64 (row q=r, k contiguous) ----
#pragma unroll
    for (int kf = 0; kf < 4; ++kf) {
      u16x4 pk;
#pragma unroll
      for (int i = 0; i < 4; ++i) pk[i] = f2bf(t4[kf][i]);
      *(u16x4*)(pw + r * 72 + kf * 16 + 4 * g) = pk;
    }

    const bf16x8 pa0 = *(const bf16x8*)(pw + r * 72 + 8 * g);
    const bf16x8 pa1 = *(const bf16x8*)(pw + r * 72 + 32 + 8 * g);

    // ---- PV: O[16q x 64h] += P * V ----
#pragma unroll
    for (int nf = 0; nf < 4; ++nf) {
      o[nf] = __builtin_amdgcn_mfma_f32_16x16x32_bf16(pa0, vv[2 * nf], o[nf], 0, 0, 0);
      o[nf] = __builtin_amdgcn_mfma_f32_16x16x32_bf16(pa1, vv[2 * nf + 1], o[nf], 0, 0, 0);
    }
  }

  // ---- write partials (o rows = 4g+i; m,l live at lane r = row) ----
#pragma unroll
  for (int nf = 0; nf < 4; ++nf)
#pragma unroll
    for (int i = 0; i < 4; ++i)
      plo[w][4 * g + i][nf * 16 + r] = o[nf][i];
  if (g == 0) {
    pml[w][0][r] = m;
    pml[w][1][r] = l;
  }
  __syncthreads();

  // ---- merge the two kv-halves; each wave writes 8 rows of one q-tile ----
  const int base = (w >> 1) << 1;
  const int hlf = w & 1;
  const int qq0 = ((base == 0) ? j : (127 - j)) << 4;
#pragma unroll
  for (int rr = 0; rr < 8; ++rr) {
    const int row = hlf * 8 + rr;
    const float mA = pml[base][0][row], mB = pml[base + 1][0][row];
    const float lA = pml[base][1][row], lB = pml[base + 1][1][row];
    const float M = fmaxf(mA, mB);
    const float ea = exp2f(mA - M), eb = exp2f(mB - M);
    const float inv = 1.f / (lA * ea + lB * eb);
    const float oo = plo[base][row][lane] * ea + plo[base + 1][row][lane] * eb;
    out[((long)(b * S_ + qq0 + row)) * H_ + lane] = oo * inv;
  }
}

extern "C" void kernel_launch(void* const* d_in, const int* in_sizes, int n_in,
                              void* d_out, int out_size, void* d_ws, size_t ws_size,
                              hipStream_t stream) {
  const float* x  = (const float*)d_in[0];
  const float* Wk = (const float*)d_in[1];
  const float* Wq = (const float*)d_in[2];
  const float* Wv = (const float*)d_in[3];
  float* out = (float*)d_out;

  u16* Qb = (u16*)d_ws;                                   // 2 MiB
  u16* Kb = Qb + (long)B_ * S_ * H_;                      // 2 MiB
  u16* Vt = Kb + (long)B_ * S_ * H_;                      // 2 MiB
  u16* Wt = Vt + (long)B_ * S_ * H_;                      // 384 KiB

  wprep_kernel<<<192, 256, 0, stream>>>(Wk, Wq, Wv, Wt);
  qkv_kernel<<<512, 512, 0, stream>>>(x, Wt, Qb, Kb, Vt);
  attn7_kernel<<<B_ * 64, 256, 0, stream>>>(Qb, Kb, Vt, out);
}